// Round 13
// baseline (252.163 us; speedup 1.0000x reference)
//
#include <hip/hip_runtime.h>

#define IMG   256
#define IMG2  65536
#define NB    64
#define NB2   128

// ---------------------------------------------------------------------------
// R13: chip-wide read/write phase separation for crops.
// Ledger: pure reads 5.6 TB/s (R11), pure writes 6.9 TB/s (R12), read-heavy
// mixed 5.8 (label), write-heavy mixed 2.3-4 (crops, 7 structures). Only
// untested variable: loads+dependent stores coexisting in time. This kernel
// loads/computes EVERYTHING into registers (phase 1), crosses a bounded-spin
// global barrier (atomic counter in d_ws; timeout-safe: data is register-
// private so the barrier affects ONLY traffic phasing, never correctness),
// then issues pure stores (phase 2, exact R12 prestore shape, 0 reads).
// 512 blocks x 256 thr, launch_bounds(256,2) -> <=256 VGPR -> 2 blocks/CU
// co-resident by construction. Stats via proven blk/cells. Label = R4.
// ---------------------------------------------------------------------------
#define WS_A8   0
#define WS_B8   65536
#define WS_A16  131072
#define WS_B16  147456
#define WS_A32  163840
#define WS_B32  167936
#define WS_BLK  172032                  // [64][64][64] float2 = 262144
#define WS_BAR_BYTES  3473408           // (172032+262144)*8 : barrier counter

__global__ __launch_bounds__(256) void blk_kernel(
    const float* __restrict__ img, float2* __restrict__ ws,
    unsigned* __restrict__ bar) {
    if (blockIdx.x == 0 && threadIdx.x == 0) bar[0] = 0u;  // reset barrier
    const int wid  = blockIdx.x * 4 + (threadIdx.x >> 6);  // 0..4095
    const int lane = threadIdx.x & 63;
    const int b    = wid >> 6;
    const int r4   = wid & 63;
    const float* __restrict__ p =
        img + (size_t)b * IMG2 + (r4 * 4) * IMG + lane * 4;
    const float4 q0 = *(const float4*)(p);
    const float4 q1 = *(const float4*)(p + IMG);
    const float4 q2 = *(const float4*)(p + 2 * IMG);
    const float4 q3 = *(const float4*)(p + 3 * IMG);
    const float mn01 = fminf(fminf(fminf(q0.x, q0.y), fminf(q0.z, q0.w)),
                             fminf(fminf(q1.x, q1.y), fminf(q1.z, q1.w)));
    const float mn23 = fminf(fminf(fminf(q2.x, q2.y), fminf(q2.z, q2.w)),
                             fminf(fminf(q3.x, q3.y), fminf(q3.z, q3.w)));
    const float mx01 = fmaxf(fmaxf(fmaxf(q0.x, q0.y), fmaxf(q0.z, q0.w)),
                             fmaxf(fmaxf(q1.x, q1.y), fmaxf(q1.z, q1.w)));
    const float mx23 = fmaxf(fmaxf(fmaxf(q2.x, q2.y), fmaxf(q2.z, q2.w)),
                             fmaxf(fmaxf(q3.x, q3.y), fmaxf(q3.z, q3.w)));
    ws[WS_BLK + (b << 12) + (r4 << 6) + lane] =
        make_float2(fminf(mn01, mn23), fmaxf(mx01, mx23));
}

template <int SH>
__device__ __forceinline__ float2 combine_blk(
    const float2* __restrict__ blk, int b, int p0, int q0) {
    float mn = 3.4e38f, mx = -3.4e38f;
    for (int i = 0; i < SH; ++i) {
#pragma unroll
        for (int j = 0; j < SH; ++j) {
            const float2 v = blk[(b << 12) + ((p0 + i) << 6) + (q0 + j)];
            mn = fminf(mn, v.x);
            mx = fmaxf(mx, v.y);
        }
    }
    return make_float2(mn, mx);
}

__device__ __forceinline__ float2 finish(float2 c, float h) {
    return make_float2(c.x, (h > 0.5f ? 1.0f : 0.0f) / (c.y - c.x + 1e-5f));
}

__global__ __launch_bounds__(256) void cells_kernel(
    const float* __restrict__ heat8,
    const float* __restrict__ heat16,
    const float* __restrict__ heat32,
    float2* __restrict__ ws) {
    const float2* __restrict__ blk = ws + WS_BLK;
    const int t = blockIdx.x * 256 + threadIdx.x;
    if (t < 131072) {                       // s8 (g=32): A then B half
        const int idx = t & 65535;
        const int half = t >> 16;
        const int b = idx >> 10, ci = (idx >> 5) & 31, cj = idx & 31;
        const int p0 = half ? max(2 * ci - 1, 0) : 2 * ci;
        const int q0 = half ? max(2 * cj - 1, 0) : 2 * cj;
        const float2 c = combine_blk<2>(blk, b, p0, q0);
        const float h = heat32[(size_t)(b + half * NB) * 1024 + ci * 32 + cj];
        ws[(half ? WS_B8 : WS_A8) + idx] = finish(c, h);
    } else if (t < 163840) {                // s16 (g=16)
        const int tt = t - 131072;
        const int idx = tt & 16383;
        const int half = tt >> 14;
        const int b = idx >> 8, ci = (idx >> 4) & 15, cj = idx & 15;
        const int p0 = half ? max(4 * ci - 1, 0) : 4 * ci;
        const int q0 = half ? max(4 * cj - 1, 0) : 4 * cj;
        const float2 c = combine_blk<4>(blk, b, p0, q0);
        const float h = heat16[(size_t)(b + half * NB) * 256 + ci * 16 + cj];
        ws[(half ? WS_B16 : WS_A16) + idx] = finish(c, h);
    } else {                                // s32 (g=8)
        const int tt = t - 163840;
        const int idx = tt & 4095;
        const int half = tt >> 12;
        const int b = idx >> 6, ci = (idx >> 3) & 7, cj = idx & 7;
        const int p0 = half ? max(8 * ci - 1, 0) : 8 * ci;
        const int q0 = half ? max(8 * cj - 1, 0) : 8 * cj;
        const float2 c = combine_blk<8>(blk, b, p0, q0);
        const float h = heat8[(size_t)(b + half * NB) * 64 + ci * 8 + cj];
        ws[(half ? WS_B32 : WS_A32) + idx] = finish(c, h);
    }
}

__device__ __forceinline__ float4 nrm(float4 q, float2 st) {
    float4 o;
    o.x = (q.x - st.x) * st.y; o.y = (q.y - st.x) * st.y;
    o.z = (q.z - st.x) * st.y; o.w = (q.w - st.x) * st.y;
    return o;
}

// Phase-separated crops: 512 blocks x 256 = 131072 threads, 8 positions each
// (position = (b,u,v0) quad). Address formulas identical to R10 (verified).
__global__ __launch_bounds__(256, 2) void crops_coop_kernel(
    const float* __restrict__ img,
    const float2* __restrict__ ws,
    float* __restrict__ out,
    unsigned* __restrict__ bar) {
    const int tid = blockIdx.x * 256 + threadIdx.x;   // 0..131071
    float4 o[8][6];

    // ---- phase 1: all loads + all compute, results register-resident ----
#pragma unroll
    for (int j = 0; j < 8; ++j) {
        const int pos = tid + j * 131072;             // 0..1048575
        const int b   = pos >> 14;
        const int u   = (pos >> 6) & 255;
        const int v0  = (pos & 63) << 2;
        const float* __restrict__ ip = img + (size_t)b * IMG2;

        const int u8  = ((u >> 3) ? (u & ~7)  - 4 : 0) + (u & 7);
        const int u16 = ((u >> 4) ? (u & ~15) - 4 : 0) + (u & 15);
        const int u32 = ((u >> 5) ? (u & ~31) - 4 : 0) + (u & 31);
        const int s8c  = (v0 < 8)  ? v0 : v0 - 4;
        const int s16c = (v0 < 16) ? v0 : v0 - 4;
        const int s32c = (v0 < 32) ? v0 : v0 - 4;

        const float4 xa  = *(const float4*)(ip + u   * IMG + v0);
        const float4 q8  = *(const float4*)(ip + u8  * IMG + s8c);
        const float4 q16 = *(const float4*)(ip + u16 * IMG + s16c);
        const float4 q32 = *(const float4*)(ip + u32 * IMG + s32c);

        const float2 a8  = ws[WS_A8  + (b << 10) + ((u >> 3) << 5) + (v0 >> 3)];
        const float2 b8  = ws[WS_B8  + (b << 10) + ((u >> 3) << 5) + (v0 >> 3)];
        const float2 a16 = ws[WS_A16 + (b << 8)  + ((u >> 4) << 4) + (v0 >> 4)];
        const float2 b16 = ws[WS_B16 + (b << 8)  + ((u >> 4) << 4) + (v0 >> 4)];
        const float2 a32 = ws[WS_A32 + (b << 6)  + ((u >> 5) << 3) + (v0 >> 5)];
        const float2 b32 = ws[WS_B32 + (b << 6)  + ((u >> 5) << 3) + (v0 >> 5)];

        o[j][0] = nrm(xa,  a8);
        o[j][1] = nrm(q8,  b8);
        o[j][2] = nrm(xa,  a16);
        o[j][3] = nrm(q16, b16);
        o[j][4] = nrm(xa,  a32);
        o[j][5] = nrm(q32, b32);
    }

    // ---- bounded-spin global barrier (traffic phasing only; data is
    //      register-private, so correctness never depends on it) ----
    __syncthreads();
    if (threadIdx.x == 0) {
        atomicAdd(bar, 1u);
        const long long t0 = clock64();
        while (atomicAdd(bar, 0u) < 512u && (clock64() - t0) < 2000000LL) {}
    }
    __syncthreads();

    // ---- phase 2: pure stores (prestore shape: contiguous 1KB per wave) --
    float* __restrict__ c32 = out;
    float* __restrict__ c16 = out + (size_t)NB2 * IMG2;
    float* __restrict__ c8  = out + (size_t)2 * NB2 * IMG2;
#pragma unroll
    for (int r = 0; r < 6; ++r) {
#pragma unroll
        for (int j = 0; j < 8; ++j) {
            const int pos = tid + j * 131072;
            const int b   = pos >> 14;
            const int u   = (pos >> 6) & 255;
            const int v0  = (pos & 63) << 2;
            float* __restrict__ base =
                (r < 2 ? c32 : (r < 4 ? c16 : c8)) +
                (size_t)(b + ((r & 1) ? NB : 0)) * IMG2;
            *(float4*)(base + u * IMG + v0) = o[j][r];
        }
    }
}

// ---------------------------------------------------------------------------
// label: one wave per row, 4 px per lane, float4 loads/stores. (R4, proven)
// ---------------------------------------------------------------------------
__device__ __forceinline__ void label_rows(
    const float* __restrict__ heat8,
    const float* __restrict__ heat16,
    const float* __restrict__ heat32,
    const float* __restrict__ seg8,
    const float* __restrict__ seg16,
    const float* __restrict__ seg32,
    float* __restrict__ out,
    int b, int u0) {
    const int wave = threadIdx.x >> 6;
    const int lane = threadIdx.x & 63;
    const int u    = u0 + wave;
    const int v0   = lane << 2;
    const int vs   = min(v0 + 4, 252);

    float nu[4] = {0.f, 0.f, 0.f, 0.f};
    float de[4] = {0.f, 0.f, 0.f, 0.f};

    if (u0 >= 32 && u0 <= 248) {
        const int i1 = u + 4;
#define SCALE_F(heat, seg, g, l, s)                                           \
        {                                                                     \
            const float* __restrict__ h1 = heat + b * (g * g);                \
            const float* __restrict__ h2 = heat + (NB + b) * (g * g);         \
            const float* __restrict__ r1 = seg + (size_t)b * IMG2 + u * IMG;  \
            const float* __restrict__ r2 =                                    \
                seg + (size_t)(NB + b) * IMG2 + i1 * IMG;                     \
            const float4 sd  = *(const float4*)(r1 + v0);                     \
            const float4 sg0 = *(const float4*)(r2 + v0);                     \
            const float4 sg1 = *(const float4*)(r2 + vs);                     \
            const float hd  = h1[(u >> l) * g + (v0 >> l)];                   \
            const float hg0 = h2[(i1 >> l) * g + (v0 >> l)];                  \
            const float hg1 = h2[(i1 >> l) * g + (vs >> l)];                  \
            const float md = (hd > 0.5f) ? 1.0f : 0.0f;                       \
            const float g0 = (hg0 > 0.5f) ? 1.0f : 0.0f;                      \
            const float g1 = (hg1 > 0.5f) ? 1.0f : 0.0f;                      \
            _Pragma("unroll")                                                 \
            for (int c = 0; c < 4; ++c) {                                     \
                const int v = v0 + c;                                         \
                const float m0 = (v < (s)) ? g0 : 0.0f;                       \
                const float m1 = (v >= (s) - 4 && v <= 251) ? g1 : 0.0f;      \
                float x = ((const float*)&sd)[c] * md;                        \
                x = fmaf(m0, ((const float*)&sg0)[c], x);                     \
                x = fmaf(m1, ((const float*)&sg1)[c], x);                     \
                nu[c] += x;                                                   \
                de[c] += md + m0 + m1;                                        \
            }                                                                 \
        }
        SCALE_F(heat32, seg32, 32, 3, 8)
        SCALE_F(heat16, seg16, 16, 4, 16)
        SCALE_F(heat8,  seg8,  8,  5, 32)
#undef SCALE_F
    } else {
        const int i0  = u;
        const int i1c = min(u + 4, 255);
#define SCALE_G(heat, seg, g, l, s)                                           \
        {                                                                     \
            const float* __restrict__ h1 = heat + b * (g * g);                \
            const float* __restrict__ h2 = heat + (NB + b) * (g * g);         \
            const float* __restrict__ r1 = seg + (size_t)b * IMG2 + u * IMG;  \
            const float* __restrict__ ra =                                    \
                seg + (size_t)(NB + b) * IMG2 + i0 * IMG;                     \
            const float* __restrict__ rb =                                    \
                seg + (size_t)(NB + b) * IMG2 + i1c * IMG;                    \
            const float4 sd  = *(const float4*)(r1 + v0);                     \
            const float4 a0q = *(const float4*)(ra + v0);                     \
            const float4 a1q = *(const float4*)(ra + vs);                     \
            const float4 b0q = *(const float4*)(rb + v0);                     \
            const float4 b1q = *(const float4*)(rb + vs);                     \
            const float hd  = h1[(u >> l) * g + (v0 >> l)];                   \
            const float hA0 = h2[(i0 >> l) * g + (v0 >> l)];                  \
            const float hA1 = h2[(i0 >> l) * g + (vs >> l)];                  \
            const float hB0 = h2[(i1c >> l) * g + (v0 >> l)];                 \
            const float hB1 = h2[(i1c >> l) * g + (vs >> l)];                 \
            const float miA = (u < (s)) ? 1.0f : 0.0f;                        \
            const float miB = (u >= (s) - 4 && u <= 251) ? 1.0f : 0.0f;       \
            const float md  = (hd > 0.5f) ? 1.0f : 0.0f;                      \
            const float gA0 = miA * ((hA0 > 0.5f) ? 1.0f : 0.0f);             \
            const float gA1 = miA * ((hA1 > 0.5f) ? 1.0f : 0.0f);             \
            const float gB0 = miB * ((hB0 > 0.5f) ? 1.0f : 0.0f);             \
            const float gB1 = miB * ((hB1 > 0.5f) ? 1.0f : 0.0f);             \
            _Pragma("unroll")                                                 \
            for (int c = 0; c < 4; ++c) {                                     \
                const int v = v0 + c;                                         \
                const float mj0 = (v < (s)) ? 1.0f : 0.0f;                    \
                const float mj1 = (v >= (s) - 4 && v <= 251) ? 1.0f : 0.0f;   \
                const float w00 = gA0 * mj0, w01 = gA1 * mj1;                 \
                const float w10 = gB0 * mj0, w11 = gB1 * mj1;                 \
                float x = ((const float*)&sd)[c] * md;                        \
                x = fmaf(w00, ((const float*)&a0q)[c], x);                    \
                x = fmaf(w01, ((const float*)&a1q)[c], x);                    \
                x = fmaf(w10, ((const float*)&b0q)[c], x);                    \
                x = fmaf(w11, ((const float*)&b1q)[c], x);                    \
                nu[c] += x;                                                   \
                de[c] += md + w00 + w01 + w10 + w11;                          \
            }                                                                 \
        }
        SCALE_G(heat32, seg32, 32, 3, 8)
        SCALE_G(heat16, seg16, 16, 4, 16)
        SCALE_G(heat8,  seg8,  8,  5, 32)
#undef SCALE_G
    }

    float4 o;
    o.x = nu[0] / (de[0] + 1e-10f);
    o.y = nu[1] / (de[1] + 1e-10f);
    o.z = nu[2] / (de[2] + 1e-10f);
    o.w = nu[3] / (de[3] + 1e-10f);
    *(float4*)(out + (size_t)b * IMG2 + u * IMG + v0) = o;
}

__global__ __launch_bounds__(256) void label_kernel(
    const float* __restrict__ heat8,
    const float* __restrict__ heat16,
    const float* __restrict__ heat32,
    const float* __restrict__ seg8,
    const float* __restrict__ seg16,
    const float* __restrict__ seg32,
    float* __restrict__ out) {
    float* label = out + (size_t)3 * NB2 * IMG2;    // (64,1,256,256)
    const int t  = blockIdx.x;                      // 0 .. 4095
    label_rows(heat8, heat16, heat32, seg8, seg16, seg32, label,
               t >> 6, (t & 63) << 2);
}

extern "C" void kernel_launch(void* const* d_in, const int* in_sizes, int n_in,
                              void* d_out, int out_size, void* d_ws, size_t ws_size,
                              hipStream_t stream) {
    const float* img    = (const float*)d_in[0];
    const float* heat8  = (const float*)d_in[1];
    const float* heat16 = (const float*)d_in[2];
    const float* heat32 = (const float*)d_in[3];
    const float* seg8   = (const float*)d_in[4];
    const float* seg16  = (const float*)d_in[5];
    const float* seg32  = (const float*)d_in[6];
    float2*   ws  = (float2*)d_ws;
    unsigned* bar = (unsigned*)((char*)d_ws + WS_BAR_BYTES);

    label_kernel<<<dim3(4096), 256, 0, stream>>>(
        heat8, heat16, heat32, seg8, seg16, seg32, (float*)d_out);
    blk_kernel<<<dim3(1024), 256, 0, stream>>>(img, ws, bar);
    cells_kernel<<<dim3(672), 256, 0, stream>>>(heat8, heat16, heat32, ws);
    crops_coop_kernel<<<dim3(512), 256, 0, stream>>>(
        img, (const float2*)ws, (float*)d_out, bar);
}